// Round 9
// baseline (154.683 us; speedup 1.0000x reference)
//
#include <hip/hip_runtime.h>

#define N_NODES 100000
#define DIM 128
#define NS 10
#define SCALE (1.0f / 11.0f)
#define NE2 ((size_t)N_NODES * 64)  // elems per column-half plane

typedef unsigned int uint;
typedef unsigned short ushort;
typedef __attribute__((ext_vector_type(8))) short bf16x8;
typedef __attribute__((ext_vector_type(4))) float f32x4;

__device__ inline float bl(uint u) {  // bf16 bits (low 16) -> float
    union { uint x; float f; } c; c.x = u << 16; return c.f;
}
__device__ inline uint f2b(float x) {  // float -> bf16 bits (RNE)
    union { float f; uint u; } c; c.f = x;
    return (c.u + 0x7FFFu + ((c.u >> 16) & 1u)) >> 16;
}

// Split W1,W2 (fp32 [128][128]) into bf16 hi/lo planes, once per launch.
__global__ __launch_bounds__(256) void wsplit(const float* __restrict__ W1,
                                              const float* __restrict__ W2,
                                              ushort* __restrict__ o) {
    const int i = blockIdx.x * 256 + threadIdx.x;  // 16384 total
    const float a = W1[i];
    uint h = f2b(a);
    o[i] = (ushort)h;
    o[16384 + i] = (ushort)f2b(a - bl(h));
    const float b = W2[i];
    h = f2b(b);
    o[32768 + i] = (ushort)h;
    o[49152 + i] = (ushort)f2b(b - bl(h));
}

// gemm1: C[r][e] = sum_k X[r][k]*W1[e][k]; bf16x3 MFMA, fp32 accum.
// C written as TWO column-half planes [N][64] (one gathered row = one
// 128B cache line for the downstream agg). Operand-swapped (W=A) so a
// lane's 4 acc regs = 4 consecutive e -> one 8B packed store.
__global__ __launch_bounds__(256, 2) void gemm1(const float* __restrict__ X,
                                                const ushort* __restrict__ Whi,
                                                const ushort* __restrict__ Wlo,
                                                ushort* __restrict__ C) {
    __shared__ __align__(16) ushort lds[8192];  // hi [0,4096), lo [4096,8192)
    const int t = threadIdx.x;
    const int lane = t & 63;
    const int wave = t >> 6;
    const int m16 = lane & 15;
    const int kq = lane >> 4;
    const int r0 = blockIdx.x * 32;  // 3125*32 == 100000, no guards

    const int v0 = t, v1 = t + 256;
    const int ln0 = v0 & 63, ln1 = v1 & 63;
    const float* s0 = X + (size_t)(r0 + (v0 >> 8) * 16 + (ln0 & 15)) * DIM +
                      ((v0 >> 6) & 3) * 32 + (ln0 >> 4) * 8;
    const float* s1 = X + (size_t)(r0 + (v1 >> 8) * 16 + (ln1 & 15)) * DIM +
                      ((v1 >> 6) & 3) * 32 + (ln1 >> 4) * 8;
    const float4 f00 = *(const float4*)(s0);
    const float4 f01 = *(const float4*)(s0 + 4);
    const float4 f10 = *(const float4*)(s1);
    const float4 f11 = *(const float4*)(s1 + 4);

    bf16x8 wh[2][4], wl[2][4];
#pragma unroll
    for (int c = 0; c < 2; ++c)
#pragma unroll
        for (int ks = 0; ks < 4; ++ks) {
            const size_t off = (size_t)((2 * wave + c) * 16 + m16) * DIM + ks * 32 + kq * 8;
            wh[c][ks] = *(const bf16x8*)(Whi + off);
            wl[c][ks] = *(const bf16x8*)(Wlo + off);
        }

    {
        const float xs[8] = {f00.x, f00.y, f00.z, f00.w, f01.x, f01.y, f01.z, f01.w};
        bf16x8 hi, lo;
#pragma unroll
        for (int j = 0; j < 8; ++j) {
            const uint hb = f2b(xs[j]);
            hi[j] = (short)hb;
            lo[j] = (short)f2b(xs[j] - bl(hb));
        }
        *(bf16x8*)(lds + (v0 >> 6) * 512 + ln0 * 8) = hi;
        *(bf16x8*)(lds + 4096 + (v0 >> 6) * 512 + ln0 * 8) = lo;
    }
    {
        const float xs[8] = {f10.x, f10.y, f10.z, f10.w, f11.x, f11.y, f11.z, f11.w};
        bf16x8 hi, lo;
#pragma unroll
        for (int j = 0; j < 8; ++j) {
            const uint hb = f2b(xs[j]);
            hi[j] = (short)hb;
            lo[j] = (short)f2b(xs[j] - bl(hb));
        }
        *(bf16x8*)(lds + (v1 >> 6) * 512 + ln1 * 8) = hi;
        *(bf16x8*)(lds + 4096 + (v1 >> 6) * 512 + ln1 * 8) = lo;
    }
    __syncthreads();

    f32x4 acc[2][2];  // [bt][c]
#pragma unroll
    for (int bt = 0; bt < 2; ++bt)
#pragma unroll
        for (int c = 0; c < 2; ++c) acc[bt][c] = (f32x4){0.f, 0.f, 0.f, 0.f};

#pragma unroll
    for (int ks = 0; ks < 4; ++ks) {
#pragma unroll
        for (int bt = 0; bt < 2; ++bt) {
            const int g = bt * 4 + ks;
            const bf16x8 xh = *(const bf16x8*)(lds + g * 512 + lane * 8);
            const bf16x8 xl = *(const bf16x8*)(lds + 4096 + g * 512 + lane * 8);
#pragma unroll
            for (int c = 0; c < 2; ++c) {
                acc[bt][c] = __builtin_amdgcn_mfma_f32_16x16x32_bf16(wh[c][ks], xh, acc[bt][c], 0, 0, 0);
                acc[bt][c] = __builtin_amdgcn_mfma_f32_16x16x32_bf16(wl[c][ks], xh, acc[bt][c], 0, 0, 0);
                acc[bt][c] = __builtin_amdgcn_mfma_f32_16x16x32_bf16(wh[c][ks], xl, acc[bt][c], 0, 0, 0);
            }
        }
    }

    // D layout: col(m16) = X-row, row(kq*4+reg) = e. Global e-col =
    // 32*wave + 16*c + 4*kq -> plane = wave>>1, in-plane col = 32*(wave&1)+16*c+4*kq.
#pragma unroll
    for (int bt = 0; bt < 2; ++bt) {
        const size_t row = (size_t)(r0 + bt * 16 + m16);
#pragma unroll
        for (int c = 0; c < 2; ++c) {
            uint2 w;
            w.x = f2b(acc[bt][c][0]) | (f2b(acc[bt][c][1]) << 16);
            w.y = f2b(acc[bt][c][2]) | (f2b(acc[bt][c][3]) << 16);
            *(uint2*)(C + (size_t)(wave >> 1) * NE2 + row * 64 +
                      (2 * (wave & 1) + c) * 16 + kq * 4) = w;
        }
    }
}

// agg1: H[i] = relu(mean(FW[{i} U adj[i]])); FW/H as two [N][64] bf16 planes.
// Two passes (one per plane, 12.8MB hot set each); indices staged once.
// Team = 16 lanes per row-pair; one row = one 128B line (16 x uint2).
__global__ __launch_bounds__(256) void agg1(const ushort* __restrict__ FW,
                                            const int* __restrict__ adj,
                                            ushort* __restrict__ H) {
    __shared__ int idx_lds[320];
    const int t = threadIdx.x;
    const int r0 = blockIdx.x * 32;  // 3125 blocks
    for (int l = t; l < 320; l += 256)
        idx_lds[l] = adj[(size_t)r0 * NS + l];  // rows r0..r0+31 contiguous
    __syncthreads();
    const int team = t >> 4;
    const int j = t & 15;
    const int ri0 = team * 2, ri1 = team * 2 + 1;
#pragma unroll
    for (int p = 0; p < 2; ++p) {
        const ushort* FWp = FW + (size_t)p * NE2;
        ushort* Hp = H + (size_t)p * NE2;
        uint2 u0[11], u1[11];
        u0[0] = ((const uint2*)(FWp + (size_t)(r0 + ri0) * 64))[j];
#pragma unroll
        for (int s = 0; s < NS; ++s)
            u0[1 + s] = ((const uint2*)(FWp + (size_t)idx_lds[ri0 * NS + s] * 64))[j];
        u1[0] = ((const uint2*)(FWp + (size_t)(r0 + ri1) * 64))[j];
#pragma unroll
        for (int s = 0; s < NS; ++s)
            u1[1 + s] = ((const uint2*)(FWp + (size_t)idx_lds[ri1 * NS + s] * 64))[j];
        float a0 = 0.f, a1 = 0.f, a2 = 0.f, a3 = 0.f;
        float b0 = 0.f, b1 = 0.f, b2 = 0.f, b3 = 0.f;
#pragma unroll
        for (int s = 0; s < 11; ++s) {
            a0 += bl(u0[s].x); a1 += bl(u0[s].x >> 16);
            a2 += bl(u0[s].y); a3 += bl(u0[s].y >> 16);
            b0 += bl(u1[s].x); b1 += bl(u1[s].x >> 16);
            b2 += bl(u1[s].y); b3 += bl(u1[s].y >> 16);
        }
        uint2 w;
        w.x = f2b(fmaxf(a0 * SCALE, 0.f)) | (f2b(fmaxf(a1 * SCALE, 0.f)) << 16);
        w.y = f2b(fmaxf(a2 * SCALE, 0.f)) | (f2b(fmaxf(a3 * SCALE, 0.f)) << 16);
        ((uint2*)(Hp + (size_t)(r0 + ri0) * 64))[j] = w;
        w.x = f2b(fmaxf(b0 * SCALE, 0.f)) | (f2b(fmaxf(b1 * SCALE, 0.f)) << 16);
        w.y = f2b(fmaxf(b2 * SCALE, 0.f)) | (f2b(fmaxf(b3 * SCALE, 0.f)) << 16);
        ((uint2*)(Hp + (size_t)(r0 + ri1) * 64))[j] = w;
    }
}

// agg2b: P[i] = mean(H[{n} U adj[n]]), n = nodes[i]; planes in, planes out,
// no relu. Same two-pass plane structure as agg1.
__global__ __launch_bounds__(256) void agg2b(const ushort* __restrict__ H,
                                             const int* __restrict__ adj,
                                             const int* __restrict__ nodes,
                                             ushort* __restrict__ P) {
    __shared__ int idx_lds[32 * 11];
    const int t = threadIdx.x;
    const int r0 = blockIdx.x * 32;  // 3125 blocks
    if (t < 32) idx_lds[t * 11] = nodes[r0 + t];
    __syncthreads();
    for (int l = t; l < 320; l += 256) {
        const int bi = l / 10;
        const int s = l - bi * 10;
        idx_lds[bi * 11 + 1 + s] = adj[(size_t)idx_lds[bi * 11] * NS + s];
    }
    __syncthreads();
    const int team = t >> 4;
    const int j = t & 15;
    const int ri0 = team * 2, ri1 = team * 2 + 1;
#pragma unroll
    for (int p = 0; p < 2; ++p) {
        const ushort* Hp = H + (size_t)p * NE2;
        ushort* Pp = P + (size_t)p * NE2;
        uint2 u0[11], u1[11];
#pragma unroll
        for (int s = 0; s < 11; ++s)
            u0[s] = ((const uint2*)(Hp + (size_t)idx_lds[ri0 * 11 + s] * 64))[j];
#pragma unroll
        for (int s = 0; s < 11; ++s)
            u1[s] = ((const uint2*)(Hp + (size_t)idx_lds[ri1 * 11 + s] * 64))[j];
        float a0 = 0.f, a1 = 0.f, a2 = 0.f, a3 = 0.f;
        float b0 = 0.f, b1 = 0.f, b2 = 0.f, b3 = 0.f;
#pragma unroll
        for (int s = 0; s < 11; ++s) {
            a0 += bl(u0[s].x); a1 += bl(u0[s].x >> 16);
            a2 += bl(u0[s].y); a3 += bl(u0[s].y >> 16);
            b0 += bl(u1[s].x); b1 += bl(u1[s].x >> 16);
            b2 += bl(u1[s].y); b3 += bl(u1[s].y >> 16);
        }
        uint2 w;
        w.x = f2b(a0 * SCALE) | (f2b(a1 * SCALE) << 16);
        w.y = f2b(a2 * SCALE) | (f2b(a3 * SCALE) << 16);
        ((uint2*)(Pp + (size_t)(r0 + ri0) * 64))[j] = w;
        w.x = f2b(b0 * SCALE) | (f2b(b1 * SCALE) << 16);
        w.y = f2b(b2 * SCALE) | (f2b(b3 * SCALE) << 16);
        ((uint2*)(Pp + (size_t)(r0 + ri1) * 64))[j] = w;
    }
}

// gemm2t: out[e][b] = relu(sum_k P[b][k]*W2[e][k]); P read from the two
// column-half planes into LDS fragment layout (linear, 0 bank conflicts),
// W2 hi/lo = B-operand in VGPRs. acc regs = 4 consecutive b -> float4 stores.
__global__ __launch_bounds__(256, 2) void gemm2t(const ushort* __restrict__ P,
                                                 const ushort* __restrict__ Whi,
                                                 const ushort* __restrict__ Wlo,
                                                 float* __restrict__ out) {
    __shared__ __align__(16) ushort lds[4096];  // 8 groups x 64 lanes x 8 bf16
    const int t = threadIdx.x;
    const int lane = t & 63;
    const int wave = t >> 6;
    const int m16 = lane & 15;
    const int kq = lane >> 4;
    const int r0 = blockIdx.x * 32;

    // slot v: bt=v>>8, ksq=(v>>6)&3, ln=v&63; row=r0+bt*16+(ln&15);
    // k0=ksq*32+(ln>>4)*8 -> plane=ksq>>1, in-plane col=(ksq&1)*32+(ln>>4)*8
    const int v0 = t, v1 = t + 256;
    const int ln0 = v0 & 63, ln1 = v1 & 63;
    const int ksq0 = (v0 >> 6) & 3, ksq1 = (v1 >> 6) & 3;
    const ushort* s0 = P + (size_t)(ksq0 >> 1) * NE2 +
                       (size_t)(r0 + (v0 >> 8) * 16 + (ln0 & 15)) * 64 +
                       (ksq0 & 1) * 32 + (ln0 >> 4) * 8;
    const ushort* s1 = P + (size_t)(ksq1 >> 1) * NE2 +
                       (size_t)(r0 + (v1 >> 8) * 16 + (ln1 & 15)) * 64 +
                       (ksq1 & 1) * 32 + (ln1 >> 4) * 8;
    const bf16x8 p0 = *(const bf16x8*)(s0);
    const bf16x8 p1 = *(const bf16x8*)(s1);

    bf16x8 wh[2][4], wl[2][4];
#pragma unroll
    for (int c = 0; c < 2; ++c)
#pragma unroll
        for (int ks = 0; ks < 4; ++ks) {
            const size_t off = (size_t)((2 * wave + c) * 16 + m16) * DIM + ks * 32 + kq * 8;
            wh[c][ks] = *(const bf16x8*)(Whi + off);
            wl[c][ks] = *(const bf16x8*)(Wlo + off);
        }

    *(bf16x8*)(lds + (v0 >> 6) * 512 + ln0 * 8) = p0;
    *(bf16x8*)(lds + (v1 >> 6) * 512 + ln1 * 8) = p1;
    __syncthreads();

    f32x4 acc[2][2];  // [bt][c]
#pragma unroll
    for (int bt = 0; bt < 2; ++bt)
#pragma unroll
        for (int c = 0; c < 2; ++c) acc[bt][c] = (f32x4){0.f, 0.f, 0.f, 0.f};

#pragma unroll
    for (int ks = 0; ks < 4; ++ks) {
#pragma unroll
        for (int bt = 0; bt < 2; ++bt) {
            const bf16x8 pa = *(const bf16x8*)(lds + (bt * 4 + ks) * 512 + lane * 8);
#pragma unroll
            for (int c = 0; c < 2; ++c) {
                acc[bt][c] = __builtin_amdgcn_mfma_f32_16x16x32_bf16(pa, wh[c][ks], acc[bt][c], 0, 0, 0);
                acc[bt][c] = __builtin_amdgcn_mfma_f32_16x16x32_bf16(pa, wl[c][ks], acc[bt][c], 0, 0, 0);
            }
        }
    }

    // D layout: col(m16) = e (B-side), row(kq*4+reg) = b (A-side)
#pragma unroll
    for (int bt = 0; bt < 2; ++bt) {
        const int b = r0 + bt * 16 + kq * 4;
#pragma unroll
        for (int c = 0; c < 2; ++c) {
            const int e = (2 * wave + c) * 16 + m16;
            float4 v;
            v.x = fmaxf(acc[bt][c][0], 0.f);
            v.y = fmaxf(acc[bt][c][1], 0.f);
            v.z = fmaxf(acc[bt][c][2], 0.f);
            v.w = fmaxf(acc[bt][c][3], 0.f);
            *(float4*)(out + (size_t)e * N_NODES + b) = v;
        }
    }
}

extern "C" void kernel_launch(void* const* d_in, const int* in_sizes, int n_in,
                              void* d_out, int out_size, void* d_ws, size_t ws_size,
                              hipStream_t stream) {
    const float* features = (const float*)d_in[0];
    const float* W1 = (const float*)d_in[1];
    const float* W2 = (const float*)d_in[2];
    const int* adj = (const int*)d_in[3];
    const int* nodes = (const int*)d_in[4];
    float* out = (float*)d_out;

    const size_t NE = (size_t)N_NODES * DIM;  // 12.8M elems (= 2 planes)
    ushort* fw = (ushort*)d_ws;   // FW1 planes, later reused as P (25.6 MB)
    ushort* h1 = fw + NE;         // h1 planes bf16 (25.6 MB)
    ushort* wpl = h1 + NE;        // 4 x 32 KB W planes
    ushort* w1hi = wpl;
    ushort* w1lo = wpl + 16384;
    ushort* w2hi = wpl + 32768;
    ushort* w2lo = wpl + 49152;

    wsplit<<<64, 256, 0, stream>>>(W1, W2, wpl);
    // FW1 = features @ W1^T (bf16x3 MFMA), written as two column-half planes
    gemm1<<<N_NODES / 32, 256, 0, stream>>>(features, w1hi, w1lo, fw);
    // h1 = relu(mean(FW1[self U adj])), per-plane passes
    agg1<<<N_NODES / 32, 256, 0, stream>>>(fw, adj, h1);
    // P = mean(h1[nodes U adj[nodes]]) (reuses fw buffer), per-plane passes
    agg2b<<<N_NODES / 32, 256, 0, stream>>>(h1, adj, nodes, fw);
    // out[e][b] = relu(P @ W2^T), coalesced transposed store
    gemm2t<<<N_NODES / 32, 256, 0, stream>>>(fw, w2hi, w2lo, out);
}

// Round 10
// 149.684 us; speedup vs baseline: 1.0334x; 1.0334x over previous
//
#include <hip/hip_runtime.h>

#define N_NODES 100000
#define DIM 128
#define NS 10
#define SCALE (1.0f / 11.0f)
#define NE2 ((size_t)N_NODES * 64)  // elems per column-half plane

typedef unsigned int uint;
typedef unsigned short ushort;
typedef __attribute__((ext_vector_type(8))) short bf16x8;
typedef __attribute__((ext_vector_type(4))) float f32x4;

__device__ inline float bl(uint u) {  // bf16 bits (low 16) -> float
    union { uint x; float f; } c; c.x = u << 16; return c.f;
}
__device__ inline uint f2b(float x) {  // float -> bf16 bits (RNE)
    union { float f; uint u; } c; c.f = x;
    return (c.u + 0x7FFFu + ((c.u >> 16) & 1u)) >> 16;
}

// Split W1,W2 (fp32 [128][128]) into bf16 hi/lo planes, once per launch.
__global__ __launch_bounds__(256) void wsplit(const float* __restrict__ W1,
                                              const float* __restrict__ W2,
                                              ushort* __restrict__ o) {
    const int i = blockIdx.x * 256 + threadIdx.x;  // 16384 total
    const float a = W1[i];
    uint h = f2b(a);
    o[i] = (ushort)h;
    o[16384 + i] = (ushort)f2b(a - bl(h));
    const float b = W2[i];
    h = f2b(b);
    o[32768 + i] = (ushort)h;
    o[49152 + i] = (ushort)f2b(b - bl(h));
}

// gemm1: C[r][e] = sum_k X[r][k]*W1[e][k]; bf16x3 MFMA, fp32 accum.
// C written as TWO column-half planes [N][64]. Operand-swapped (W=A) so a
// lane's 4 acc regs = 4 consecutive e -> one 8B packed store. (unchanged)
__global__ __launch_bounds__(256, 2) void gemm1(const float* __restrict__ X,
                                                const ushort* __restrict__ Whi,
                                                const ushort* __restrict__ Wlo,
                                                ushort* __restrict__ C) {
    __shared__ __align__(16) ushort lds[8192];  // hi [0,4096), lo [4096,8192)
    const int t = threadIdx.x;
    const int lane = t & 63;
    const int wave = t >> 6;
    const int m16 = lane & 15;
    const int kq = lane >> 4;
    const int r0 = blockIdx.x * 32;  // 3125*32 == 100000, no guards

    const int v0 = t, v1 = t + 256;
    const int ln0 = v0 & 63, ln1 = v1 & 63;
    const float* s0 = X + (size_t)(r0 + (v0 >> 8) * 16 + (ln0 & 15)) * DIM +
                      ((v0 >> 6) & 3) * 32 + (ln0 >> 4) * 8;
    const float* s1 = X + (size_t)(r0 + (v1 >> 8) * 16 + (ln1 & 15)) * DIM +
                      ((v1 >> 6) & 3) * 32 + (ln1 >> 4) * 8;
    const float4 f00 = *(const float4*)(s0);
    const float4 f01 = *(const float4*)(s0 + 4);
    const float4 f10 = *(const float4*)(s1);
    const float4 f11 = *(const float4*)(s1 + 4);

    bf16x8 wh[2][4], wl[2][4];
#pragma unroll
    for (int c = 0; c < 2; ++c)
#pragma unroll
        for (int ks = 0; ks < 4; ++ks) {
            const size_t off = (size_t)((2 * wave + c) * 16 + m16) * DIM + ks * 32 + kq * 8;
            wh[c][ks] = *(const bf16x8*)(Whi + off);
            wl[c][ks] = *(const bf16x8*)(Wlo + off);
        }

    {
        const float xs[8] = {f00.x, f00.y, f00.z, f00.w, f01.x, f01.y, f01.z, f01.w};
        bf16x8 hi, lo;
#pragma unroll
        for (int j = 0; j < 8; ++j) {
            const uint hb = f2b(xs[j]);
            hi[j] = (short)hb;
            lo[j] = (short)f2b(xs[j] - bl(hb));
        }
        *(bf16x8*)(lds + (v0 >> 6) * 512 + ln0 * 8) = hi;
        *(bf16x8*)(lds + 4096 + (v0 >> 6) * 512 + ln0 * 8) = lo;
    }
    {
        const float xs[8] = {f10.x, f10.y, f10.z, f10.w, f11.x, f11.y, f11.z, f11.w};
        bf16x8 hi, lo;
#pragma unroll
        for (int j = 0; j < 8; ++j) {
            const uint hb = f2b(xs[j]);
            hi[j] = (short)hb;
            lo[j] = (short)f2b(xs[j] - bl(hb));
        }
        *(bf16x8*)(lds + (v1 >> 6) * 512 + ln1 * 8) = hi;
        *(bf16x8*)(lds + 4096 + (v1 >> 6) * 512 + ln1 * 8) = lo;
    }
    __syncthreads();

    f32x4 acc[2][2];  // [bt][c]
#pragma unroll
    for (int bt = 0; bt < 2; ++bt)
#pragma unroll
        for (int c = 0; c < 2; ++c) acc[bt][c] = (f32x4){0.f, 0.f, 0.f, 0.f};

#pragma unroll
    for (int ks = 0; ks < 4; ++ks) {
#pragma unroll
        for (int bt = 0; bt < 2; ++bt) {
            const int g = bt * 4 + ks;
            const bf16x8 xh = *(const bf16x8*)(lds + g * 512 + lane * 8);
            const bf16x8 xl = *(const bf16x8*)(lds + 4096 + g * 512 + lane * 8);
#pragma unroll
            for (int c = 0; c < 2; ++c) {
                acc[bt][c] = __builtin_amdgcn_mfma_f32_16x16x32_bf16(wh[c][ks], xh, acc[bt][c], 0, 0, 0);
                acc[bt][c] = __builtin_amdgcn_mfma_f32_16x16x32_bf16(wl[c][ks], xh, acc[bt][c], 0, 0, 0);
                acc[bt][c] = __builtin_amdgcn_mfma_f32_16x16x32_bf16(wh[c][ks], xl, acc[bt][c], 0, 0, 0);
            }
        }
    }

    // D layout: col(m16) = X-row, row(kq*4+reg) = e. Global e-col =
    // 32*wave + 16*c + 4*kq -> plane = wave>>1, in-plane col = 32*(wave&1)+16*c+4*kq.
#pragma unroll
    for (int bt = 0; bt < 2; ++bt) {
        const size_t row = (size_t)(r0 + bt * 16 + m16);
#pragma unroll
        for (int c = 0; c < 2; ++c) {
            uint2 w;
            w.x = f2b(acc[bt][c][0]) | (f2b(acc[bt][c][1]) << 16);
            w.y = f2b(acc[bt][c][2]) | (f2b(acc[bt][c][3]) << 16);
            *(uint2*)(C + (size_t)(wave >> 1) * NE2 + row * 64 +
                      (2 * (wave & 1) + c) * 16 + kq * 4) = w;
        }
    }
}

// agg1: H[i] = relu(mean(FW[{i} U adj[i]])); FW/H as two [N][64] bf16 planes.
// (unchanged — at the L2-miss-path wall)
__global__ __launch_bounds__(256) void agg1(const ushort* __restrict__ FW,
                                            const int* __restrict__ adj,
                                            ushort* __restrict__ H) {
    __shared__ int idx_lds[320];
    const int t = threadIdx.x;
    const int r0 = blockIdx.x * 32;  // 3125 blocks
    for (int l = t; l < 320; l += 256)
        idx_lds[l] = adj[(size_t)r0 * NS + l];  // rows r0..r0+31 contiguous
    __syncthreads();
    const int team = t >> 4;
    const int j = t & 15;
    const int ri0 = team * 2, ri1 = team * 2 + 1;
#pragma unroll
    for (int p = 0; p < 2; ++p) {
        const ushort* FWp = FW + (size_t)p * NE2;
        ushort* Hp = H + (size_t)p * NE2;
        uint2 u0[11], u1[11];
        u0[0] = ((const uint2*)(FWp + (size_t)(r0 + ri0) * 64))[j];
#pragma unroll
        for (int s = 0; s < NS; ++s)
            u0[1 + s] = ((const uint2*)(FWp + (size_t)idx_lds[ri0 * NS + s] * 64))[j];
        u1[0] = ((const uint2*)(FWp + (size_t)(r0 + ri1) * 64))[j];
#pragma unroll
        for (int s = 0; s < NS; ++s)
            u1[1 + s] = ((const uint2*)(FWp + (size_t)idx_lds[ri1 * NS + s] * 64))[j];
        float a0 = 0.f, a1 = 0.f, a2 = 0.f, a3 = 0.f;
        float b0 = 0.f, b1 = 0.f, b2 = 0.f, b3 = 0.f;
#pragma unroll
        for (int s = 0; s < 11; ++s) {
            a0 += bl(u0[s].x); a1 += bl(u0[s].x >> 16);
            a2 += bl(u0[s].y); a3 += bl(u0[s].y >> 16);
            b0 += bl(u1[s].x); b1 += bl(u1[s].x >> 16);
            b2 += bl(u1[s].y); b3 += bl(u1[s].y >> 16);
        }
        uint2 w;
        w.x = f2b(fmaxf(a0 * SCALE, 0.f)) | (f2b(fmaxf(a1 * SCALE, 0.f)) << 16);
        w.y = f2b(fmaxf(a2 * SCALE, 0.f)) | (f2b(fmaxf(a3 * SCALE, 0.f)) << 16);
        ((uint2*)(Hp + (size_t)(r0 + ri0) * 64))[j] = w;
        w.x = f2b(fmaxf(b0 * SCALE, 0.f)) | (f2b(fmaxf(b1 * SCALE, 0.f)) << 16);
        w.y = f2b(fmaxf(b2 * SCALE, 0.f)) | (f2b(fmaxf(b3 * SCALE, 0.f)) << 16);
        ((uint2*)(Hp + (size_t)(r0 + ri1) * 64))[j] = w;
    }
}

// gemm2f2: fused layer-2. 512 threads, 32 b-rows/block. Thread t gathers
// EXACTLY the (row, 16B k-chunk) that P-fragment slot t needs:
//   row = (t>>8)*16 + (t&15), k0 = ((t>>6)&3)*32 + ((t>>4)&3)*8
// -> LDS staging write is plds + t*16B (linear, ZERO bank conflicts; this
// was r6's 1.43M-conflict scatter). Then MFMA (P=A, W2 hi/lo=B), 1 e-tile
// per wave, and relu float4 stores to out[e][b] (64B/row contiguous).
// P is never materialized in global memory.
__global__ __launch_bounds__(512) void gemm2f2(const ushort* __restrict__ H,
                                               const int* __restrict__ adj,
                                               const int* __restrict__ nodes,
                                               const ushort* __restrict__ Whi,
                                               const ushort* __restrict__ Wlo,
                                               float* __restrict__ out) {
    __shared__ __align__(16) ushort plds[4096];  // 512 slots x 8 bf16 = 8KB
    __shared__ int idx_lds[32 * 11];
    const int t = threadIdx.x;
    const int lane = t & 63;
    const int wave = t >> 6;   // 0..7 -> e-tile
    const int m16 = lane & 15;
    const int kq = lane >> 4;  // 0..3
    const int r0 = blockIdx.x * 32;  // 3125 blocks

    // W2 fragments (B-operand) for this wave's e-tile: L2-hot, issued early.
    bf16x8 wh[4], wl[4];
#pragma unroll
    for (int ks = 0; ks < 4; ++ks) {
        const size_t off = (size_t)(wave * 16 + m16) * DIM + ks * 32 + kq * 8;
        wh[ks] = *(const bf16x8*)(Whi + off);
        wl[ks] = *(const bf16x8*)(Wlo + off);
    }

    if (t < 32) idx_lds[t * 11] = nodes[r0 + t];
    __syncthreads();
    if (t < 320) {
        const int bi = t / 10;
        const int s = t - bi * 10;
        idx_lds[bi * 11 + 1 + s] = adj[(size_t)idx_lds[bi * 11] * NS + s];
    }
    __syncthreads();

    // Gather + mean: 11 x 16B from the h1 planes (plane = k0>>6).
    const int ri = (t >> 8) * 16 + (t & 15);
    const int k0 = ((t >> 6) & 3) * 32 + ((t >> 4) & 3) * 8;
    const ushort* Hp = H + (size_t)(k0 >> 6) * NE2 + (k0 & 63);
    uint4 u[11];
#pragma unroll
    for (int s = 0; s < 11; ++s)
        u[s] = *(const uint4*)(Hp + (size_t)idx_lds[ri * 11 + s] * 64);
    float a[8];
#pragma unroll
    for (int k = 0; k < 8; ++k) a[k] = 0.f;
#pragma unroll
    for (int s = 0; s < 11; ++s) {
        a[0] += bl(u[s].x); a[1] += bl(u[s].x >> 16);
        a[2] += bl(u[s].y); a[3] += bl(u[s].y >> 16);
        a[4] += bl(u[s].z); a[5] += bl(u[s].z >> 16);
        a[6] += bl(u[s].w); a[7] += bl(u[s].w >> 16);
    }
    bf16x8 pw;
#pragma unroll
    for (int k = 0; k < 8; ++k) pw[k] = (short)f2b(a[k] * SCALE);
    *(bf16x8*)(plds + t * 8) = pw;  // slot t: linear, conflict-free
    __syncthreads();

    // MFMA phase: acc[bt] over bt row-tiles; A-frag slot = (bt*4+ks)*64+lane.
    f32x4 acc[2];
    acc[0] = (f32x4){0.f, 0.f, 0.f, 0.f};
    acc[1] = (f32x4){0.f, 0.f, 0.f, 0.f};
#pragma unroll
    for (int ks = 0; ks < 4; ++ks) {
#pragma unroll
        for (int bt = 0; bt < 2; ++bt) {
            const bf16x8 pa = *(const bf16x8*)(plds + (bt * 4 + ks) * 512 + lane * 8);
            acc[bt] = __builtin_amdgcn_mfma_f32_16x16x32_bf16(pa, wh[ks], acc[bt], 0, 0, 0);
            acc[bt] = __builtin_amdgcn_mfma_f32_16x16x32_bf16(pa, wl[ks], acc[bt], 0, 0, 0);
        }
    }

    // D layout: col(m16) = e (B-side), row(kq*4+reg) = b (A-side).
    const int e = wave * 16 + m16;
#pragma unroll
    for (int bt = 0; bt < 2; ++bt) {
        const int b = r0 + bt * 16 + kq * 4;
        float4 v;
        v.x = fmaxf(acc[bt][0], 0.f);
        v.y = fmaxf(acc[bt][1], 0.f);
        v.z = fmaxf(acc[bt][2], 0.f);
        v.w = fmaxf(acc[bt][3], 0.f);
        *(float4*)(out + (size_t)e * N_NODES + b) = v;
    }
}

extern "C" void kernel_launch(void* const* d_in, const int* in_sizes, int n_in,
                              void* d_out, int out_size, void* d_ws, size_t ws_size,
                              hipStream_t stream) {
    const float* features = (const float*)d_in[0];
    const float* W1 = (const float*)d_in[1];
    const float* W2 = (const float*)d_in[2];
    const int* adj = (const int*)d_in[3];
    const int* nodes = (const int*)d_in[4];
    float* out = (float*)d_out;

    const size_t NE = (size_t)N_NODES * DIM;  // 12.8M elems (= 2 planes)
    ushort* fw = (ushort*)d_ws;   // FW1 planes bf16 (25.6 MB)
    ushort* h1 = fw + NE;         // h1 planes bf16 (25.6 MB)
    ushort* wpl = h1 + NE;        // 4 x 32 KB W planes
    ushort* w1hi = wpl;
    ushort* w1lo = wpl + 16384;
    ushort* w2hi = wpl + 32768;
    ushort* w2lo = wpl + 49152;

    wsplit<<<64, 256, 0, stream>>>(W1, W2, wpl);
    // FW1 = features @ W1^T (bf16x3 MFMA), written as two column-half planes
    gemm1<<<N_NODES / 32, 256, 0, stream>>>(features, w1hi, w1lo, fw);
    // h1 = relu(mean(FW1[self U adj])), per-plane passes
    agg1<<<N_NODES / 32, 256, 0, stream>>>(fw, adj, h1);
    // out[e][b] = relu((mean h1[nodes U adj[nodes]]) @ W2^T) — fused, P stays on-chip
    gemm2f2<<<N_NODES / 32, 512, 0, stream>>>(h1, adj, nodes, w2hi, w2lo, out);
}